// Round 6
// baseline (4731.619 us; speedup 1.0000x reference)
//
#include <hip/hip_runtime.h>
#include <hip/hip_bf16.h>

// Problem constants (fixed by reference)
#define SEQ    2048
#define BATCH  2
#define MROWS  (SEQ*BATCH)    // 4096
#define EMBED  1024
#define KCTX   3
#define XDIM   (KCTX*EMBED)   // 3072
#define VOCAB  50257
#define VPAD   50304          // Wout^T rows allocated (multiple of 128)
#define GK     1024           // K of the logits GEMM
#define NT2    32             // K-tiles of BK=32
#define NBLKN  197            // ceil(VOCAB/256)
#define NWG    (16*NBLKN)     // 3152 blocks, divisible by 8

using u16 = unsigned short;
typedef __attribute__((ext_vector_type(8))) short   frag_ab;  // 8 bf16
typedef __attribute__((ext_vector_type(4))) float   frag_cd;  // 4 f32
typedef float f32x4u __attribute__((ext_vector_type(4), aligned(4)));

__device__ __forceinline__ u16 f2bf(float f) {
  union { float f; unsigned u; } v; v.f = f;
  unsigned r = v.u + 0x7fffu + ((v.u >> 16) & 1u);
  return (u16)(r >> 16);
}

__device__ __forceinline__ void gload16(const u16* g, u16* l) {
  __builtin_amdgcn_global_load_lds((const __attribute__((address_space(1))) void*)g,
                                   (__attribute__((address_space(3))) void*)l, 16, 0, 0);
}

// ---------------------------------------------------------------------------
// Gather: XB[r][i*1024+c] = bf16(E[tok(r,i)][c]); r = s*BATCH+b
// ---------------------------------------------------------------------------
__global__ void gather_x(const int* __restrict__ tokens,
                         const float* __restrict__ E,
                         u16* __restrict__ XB) {
  const int r = blockIdx.x;
  const int s = r >> 1, b = r & 1;
  #pragma unroll
  for (int i = 0; i < KCTX; ++i) {
    int t = s + i - (KCTX - 1);
    int tok = (t >= 0) ? tokens[t * BATCH + b] : 0;
    const float* src = &E[(size_t)tok * EMBED];
    u16* dst = &XB[(size_t)r * XDIM + i * EMBED];
    int c = threadIdx.x * 4;
    float4 v = *(const float4*)&src[c];
    u16 o[4] = { f2bf(v.x), f2bf(v.y), f2bf(v.z), f2bf(v.w) };
    *(ulong1*)&dst[c] = *(ulong1*)o;
  }
}

// ---------------------------------------------------------------------------
// Transpose + f32->bf16: W (K x N) -> WT (Npad x K). n >= N writes 0.
// ---------------------------------------------------------------------------
__global__ void transpose_cvt(const float* __restrict__ W,
                              u16* __restrict__ WT,
                              int K, int N) {
  __shared__ float tile[32][33];
  const int nb = blockIdx.x * 32, kb = blockIdx.y * 32;
  const int tx = threadIdx.x & 31, ty = threadIdx.x >> 5;
  #pragma unroll
  for (int i = 0; i < 32; i += 8) {
    int k = kb + ty + i, n = nb + tx;
    tile[ty + i][tx] = (n < N) ? W[(size_t)k * N + n] : 0.f;
  }
  __syncthreads();
  #pragma unroll
  for (int i = 0; i < 32; i += 8) {
    int n = nb + ty + i, k = kb + tx;
    WT[(size_t)n * K + k] = f2bf(tile[tx][ty + i]);
  }
}

// ---------------------------------------------------------------------------
// 128x128-tile GEMM (2-phase) for the two small GEMMs. Verified round 1.
// ---------------------------------------------------------------------------
template<int EPI>
__global__ __launch_bounds__(256, 2)
void gemm_bt(const u16* __restrict__ A, const u16* __restrict__ BT,
             const float* __restrict__ bias, void* __restrict__ Cout,
             int K, int Nout) {
  __shared__ u16 lA[128 * 64];
  __shared__ u16 lB[128 * 64];
  const int tid  = threadIdx.x;
  const int wave = tid >> 6, lane = tid & 63;
  const int m0 = blockIdx.y * 128;
  const int n0 = blockIdx.x * 128;
  const int wm = (wave >> 1) * 64;
  const int wn = (wave & 1) * 64;

  frag_cd acc[4][4];
  #pragma unroll
  for (int i = 0; i < 4; ++i)
    #pragma unroll
    for (int j = 0; j < 4; ++j)
      acc[i][j] = (frag_cd)0.f;

  const int srow = lane >> 3;
  const int skc  = (lane & 7) * 8;

  for (int k0 = 0; k0 < K; k0 += 64) {
    #pragma unroll
    for (int i = 0; i < 4; ++i) {
      int chunk = wave * 4 + i;
      int r = chunk * 8 + srow;
      const u16* ga = &A [(size_t)(m0 + r) * K + k0 + skc];
      const u16* gb = &BT[(size_t)(n0 + r) * K + k0 + skc];
      gload16(ga, &lA[chunk * 512 + lane * 8]);
      gload16(gb, &lB[chunk * 512 + lane * 8]);
    }
    __syncthreads();

    #pragma unroll
    for (int kk = 0; kk < 2; ++kk) {
      const int ko = kk * 32 + (lane >> 4) * 8;
      frag_ab af[4], bfr[4];
      #pragma unroll
      for (int i = 0; i < 4; ++i) {
        af[i]  = *(const frag_ab*)&lA[(wm + i * 16 + (lane & 15)) * 64 + ko];
        bfr[i] = *(const frag_ab*)&lB[(wn + i * 16 + (lane & 15)) * 64 + ko];
      }
      #pragma unroll
      for (int i = 0; i < 4; ++i)
        #pragma unroll
        for (int j = 0; j < 4; ++j)
          acc[i][j] = __builtin_amdgcn_mfma_f32_16x16x32_bf16(
              af[i], bfr[j], acc[i][j], 0, 0, 0);
    }
    __syncthreads();
  }

  const int cr = (lane >> 4) * 4;
  const int cc = lane & 15;
  if (EPI == 0) {
    u16* H = (u16*)Cout;
    #pragma unroll
    for (int j = 0; j < 4; ++j) {
      int colg = n0 + wn + j * 16 + cc;
      float bv = bias[colg];
      #pragma unroll
      for (int i = 0; i < 4; ++i)
        #pragma unroll
        for (int t = 0; t < 4; ++t) {
          int rowg = m0 + wm + i * 16 + cr + t;
          float v = acc[i][j][t] + bv;
          v = v / (1.f + __expf(-v));
          H[(size_t)rowg * Nout + colg] = f2bf(v);
        }
    }
  } else {
    float* O = (float*)Cout;
    #pragma unroll
    for (int j = 0; j < 4; ++j) {
      int colg = n0 + wn + j * 16 + cc;
      if (colg < Nout) {
        float bv = bias[colg];
        #pragma unroll
        for (int i = 0; i < 4; ++i)
          #pragma unroll
          for (int t = 0; t < 4; ++t) {
            int rowg = m0 + wm + i * 16 + cr + t;
            O[(size_t)rowg * Nout + colg] = acc[i][j][t] + bv;
          }
      }
    }
  }
}

// ---------------------------------------------------------------------------
// Logits GEMM, round 6: 256x256 tile, BK=32, 64 KiB LDS => 2 blocks/CU (TLP),
// swapped-operand MFMA => coalesced float4 epilogue.
//
// LDS map (bytes): H2 tile par0 @0, par1 @16384; WOT tile par0 @32768,
// par1 @49152. Row = 64 B (32 bf16). Swizzle: 16B-slot ^= (row>>1)&3,
// applied as pre-swizzled global source + XOR'd ds_read (both-sides rule).
//
// Per K-tile: stage 4 gloads (next parity) -> 12 asm ds_reads -> lgkm0 ->
// 32 MFMA (D = WOT_frag x H2_frag: D-row = vocab dim => lane's 4 acc regs
// are 4 consecutive vocab cols of one output row) -> vmcnt(0) -> barrier.
// One barrier per tile; cross-block TLP hides stage latency + epilogue.
// ---------------------------------------------------------------------------
#define BARR   asm volatile("s_barrier" ::: "memory")
#define VMCNT0 asm volatile("s_waitcnt vmcnt(0)" ::: "memory")
#define LGKM0  asm volatile("s_waitcnt lgkmcnt(0)" ::: "memory")
#define SCHED0 __builtin_amdgcn_sched_barrier(0)
#define PRIO1  __builtin_amdgcn_s_setprio(1)
#define PRIO0  __builtin_amdgcn_s_setprio(0)

#define DSREAD(DST, AREG, IMM) \
  asm volatile("ds_read_b128 %0, %1 offset:%2" : "=v"(DST) : "v"(AREG), "i"(IMM))

#define STAGE4(WP) { \
  gload16(pa0, (u16*)(smraw + (WP)         + stoff)); \
  gload16(pa1, (u16*)(smraw + (WP) +  8192 + stoff)); \
  gload16(pb0, (u16*)(smraw + (WP) + 32768 + stoff)); \
  gload16(pb1, (u16*)(smraw + (WP) + 40960 + stoff)); }

#define ADV { pa0 += 32; pa1 += 32; pb0 += 32; pb1 += 32; }

#define KTILE(PAR) { \
  STAGE4((PAR ^ 1) * 16384); \
  DSREAD(aW[0], bWreg, (PAR)*16384 + 32768 + 0*1024); \
  DSREAD(aW[1], bWreg, (PAR)*16384 + 32768 + 1*1024); \
  DSREAD(aW[2], bWreg, (PAR)*16384 + 32768 + 2*1024); \
  DSREAD(aW[3], bWreg, (PAR)*16384 + 32768 + 3*1024); \
  DSREAD(bH[0], bHreg, (PAR)*16384 + 0*1024); \
  DSREAD(bH[1], bHreg, (PAR)*16384 + 1*1024); \
  DSREAD(bH[2], bHreg, (PAR)*16384 + 2*1024); \
  DSREAD(bH[3], bHreg, (PAR)*16384 + 3*1024); \
  DSREAD(bH[4], bHreg, (PAR)*16384 + 4*1024); \
  DSREAD(bH[5], bHreg, (PAR)*16384 + 5*1024); \
  DSREAD(bH[6], bHreg, (PAR)*16384 + 6*1024); \
  DSREAD(bH[7], bHreg, (PAR)*16384 + 7*1024); \
  LGKM0; SCHED0; \
  PRIO1; \
  _Pragma("unroll") for (int nf = 0; nf < 4; ++nf) \
  _Pragma("unroll") for (int mf = 0; mf < 8; ++mf) \
    acc[nf][mf] = __builtin_amdgcn_mfma_f32_16x16x32_bf16(aW[nf], bH[mf], acc[nf][mf], 0, 0, 0); \
  PRIO0; SCHED0; \
  VMCNT0; BARR; \
  ADV; }

__global__ __launch_bounds__(512, 4)
void gemm256(const u16* __restrict__ A, const u16* __restrict__ BT,
             const float* __restrict__ bias, float* __restrict__ O) {
  extern __shared__ char smraw[];

  // Bijective chunked XCD swizzle; M-innermost so one XCD reuses one B-panel.
  const int bid = blockIdx.x;
  const int wg  = (bid & 7) * (NWG / 8) + (bid >> 3);
  const int m0  = (wg & 15) * 256;
  const int n0  = (wg >> 4) * 256;

  const int tid  = threadIdx.x;
  const int lane = tid & 63, wave = tid >> 6;
  const int wm = wave >> 2, wn = wave & 3;   // 2 x 4 waves

  // ---- staging constants (gload_lds dest = base + lane*16: linear) ----
  const int stoff = wave * 1024 + lane * 16;               // LDS byte offset
  const int srow  = wave * 16 + (lane >> 2);               // tile row (+g*128)
  const int ke    = ((lane & 3) ^ ((lane >> 3) & 3)) * 8;  // pre-swz k elems

  const u16* pa0 = A + (size_t)(m0 + srow      ) * GK + ke;
  const u16* pa1 = A + (size_t)(m0 + srow + 128) * GK + ke;
  int rb0 = n0 + srow;       if (rb0 > VPAD - 1) rb0 = VPAD - 1;
  int rb1 = n0 + srow + 128; if (rb1 > VPAD - 1) rb1 = VPAD - 1;
  const u16* pb0 = BT + (size_t)rb0 * GK + ke;
  const u16* pb1 = BT + (size_t)rb1 * GK + ke;

  // ---- ds_read address regs (slot ^= (row>>1)&3; row = base + (lane&15)) --
  const unsigned dynbase = (unsigned)(size_t)(__attribute__((address_space(3))) char*)smraw;
  const int c = lane & 15, q = lane >> 4;
  const unsigned swq  = ((unsigned)q << 4) ^ (((unsigned)(c >> 1) & 3u) << 4);
  const unsigned bWreg = dynbase + (unsigned)((wn * 64  + c) * 64) + swq;  // WOT rows (vocab)
  const unsigned bHreg = dynbase + (unsigned)((wm * 128 + c) * 64) + swq;  // H2 rows (m)

  frag_ab aW[4], bH[8];
  frag_cd acc[4][8];
  #pragma unroll
  for (int i = 0; i < 4; ++i)
    #pragma unroll
    for (int j = 0; j < 8; ++j)
      acc[i][j] = (frag_cd)0.f;

  // ---- prologue: stage tile 0 into parity 0 ----
  STAGE4(0);
  ADV;
  VMCNT0; BARR;

  // ---- main loop: 32 K-tiles, parity double-buffered ----
  #pragma unroll 1
  for (int tt = 0; tt < NT2 / 2; ++tt) {
    KTILE(0);
    KTILE(1);
  }

  asm volatile("s_waitcnt vmcnt(0) lgkmcnt(0)" ::: "memory");

  // ---- epilogue: D-row = vocab dim -> float4 stores (4 consecutive cols) --
  const int cr = q * 4;                       // vocab sub-offset
  const int colbase = n0 + wn * 64;
  if (colbase + 64 <= VOCAB) {
    #pragma unroll
    for (int nf = 0; nf < 4; ++nf) {
      const int col = colbase + nf * 16 + cr;
      frag_cd bv = *(const frag_cd*)&bias[col];   // col%4==0, bias 16B-aligned
      #pragma unroll
      for (int mf = 0; mf < 8; ++mf) {
        const int row = m0 + wm * 128 + mf * 16 + c;
        frag_cd v = acc[nf][mf] + bv;
        *(f32x4u*)&O[(size_t)row * VOCAB + col] = *(f32x4u*)&v;
      }
    }
  } else {
    #pragma unroll
    for (int nf = 0; nf < 4; ++nf) {
      const int col = colbase + nf * 16 + cr;
      #pragma unroll
      for (int t = 0; t < 4; ++t) {
        if (col + t < VOCAB) {
          const float bv = bias[col + t];
          #pragma unroll
          for (int mf = 0; mf < 8; ++mf) {
            const int row = m0 + wm * 128 + mf * 16 + c;
            O[(size_t)row * VOCAB + col + t] = acc[nf][mf][t] + bv;
          }
        }
      }
    }
  }
}

// ---------------------------------------------------------------------------
extern "C" void kernel_launch(void* const* d_in, const int* in_sizes, int n_in,
                              void* d_out, int out_size, void* d_ws, size_t ws_size,
                              hipStream_t stream) {
  const int*   tokens = (const int*)  d_in[0];
  const float* E      = (const float*)d_in[1];
  const float* W1     = (const float*)d_in[2];
  const float* b1     = (const float*)d_in[3];
  const float* W2     = (const float*)d_in[4];
  const float* b2     = (const float*)d_in[5];
  const float* Wout   = (const float*)d_in[6];
  const float* bout   = (const float*)d_in[7];
  float* out = (float*)d_out;

  // Workspace layout (~153.4 MB). Order chosen so gemm256's harmless
  // last-tile over-advance reads (<=1 KB past H2 / WOT) land inside ws.
  char* p = (char*)d_ws;
  u16* XB  = (u16*)p; p += (size_t)MROWS * XDIM  * 2;   // 25.2 MB
  u16* WOT = (u16*)p; p += (size_t)VPAD  * EMBED * 2;   // 103.0 MB (over-read -> H1)
  u16* H1  = (u16*)p; p += (size_t)MROWS * EMBED * 2;   //  8.4 MB
  u16* H2  = (u16*)p; p += (size_t)MROWS * EMBED * 2;   //  8.4 MB (over-read -> W1T)
  u16* W1T = (u16*)p; p += (size_t)EMBED * XDIM  * 2;   //  6.3 MB
  u16* W2T = (u16*)p; p += (size_t)EMBED * EMBED * 2;   //  2.1 MB

  hipFuncSetAttribute((const void*)gemm256,
                      hipFuncAttributeMaxDynamicSharedMemorySize, 65536);

  gather_x<<<MROWS, 256, 0, stream>>>(tokens, E, XB);
  transpose_cvt<<<dim3(EMBED/32, XDIM/32),  256, 0, stream>>>(W1,   W1T, XDIM,  EMBED);
  transpose_cvt<<<dim3(EMBED/32, EMBED/32), 256, 0, stream>>>(W2,   W2T, EMBED, EMBED);
  transpose_cvt<<<dim3(VPAD/32,  EMBED/32), 256, 0, stream>>>(Wout, WOT, EMBED, VOCAB);

  gemm_bt<0><<<dim3(EMBED/128, MROWS/128), 256, 0, stream>>>(XB, W1T, b1, H1, XDIM,  EMBED);
  gemm_bt<0><<<dim3(EMBED/128, MROWS/128), 256, 0, stream>>>(H1, W2T, b2, H2, EMBED, EMBED);

  gemm256<<<NWG, 512, 65536, stream>>>(H2, WOT, bout, out);
}